// Round 1
// baseline (781.071 us; speedup 1.0000x reference)
//
#include <hip/hip_runtime.h>
#include <hip/hip_bf16.h>

#define N_NODES  50000
#define N_EDGES  800000
#define DIM      64
#define N_GRAPHS 64
#define OUT_DIM  10
#define NBLK_N   196   // ceil(50000/256)

// ---------------- CSR build ----------------

__global__ __launch_bounds__(256) void count_kernel(const int* __restrict__ dst,
                                                    int* __restrict__ cnt) {
    int e = blockIdx.x * 256 + threadIdx.x;
    if (e < N_EDGES) atomicAdd(&cnt[dst[e]], 1);
}

__global__ __launch_bounds__(256) void scan1(const int* __restrict__ cnt,
                                             int* __restrict__ offs,
                                             int* __restrict__ bsums) {
    __shared__ int s[256];
    int t = threadIdx.x;
    int i = blockIdx.x * 256 + t;
    int v = (i < N_NODES) ? cnt[i] : 0;
    s[t] = v;
    __syncthreads();
    for (int d = 1; d < 256; d <<= 1) {
        int tmp = (t >= d) ? s[t - d] : 0;
        __syncthreads();
        s[t] += tmp;
        __syncthreads();
    }
    if (i < N_NODES) offs[i] = s[t] - v;   // exclusive
    if (t == 255) bsums[blockIdx.x] = s[255];
}

__global__ void scan2(int* bsums, int nb) {
    __shared__ int s[256];
    int t = threadIdx.x;
    int v = (t < nb) ? bsums[t] : 0;
    s[t] = v;
    __syncthreads();
    for (int d = 1; d < 256; d <<= 1) {
        int tmp = (t >= d) ? s[t - d] : 0;
        __syncthreads();
        s[t] += tmp;
        __syncthreads();
    }
    if (t < nb) bsums[t] = s[t] - v;       // exclusive
}

__global__ __launch_bounds__(256) void scan3(int* __restrict__ offs,
                                             const int* __restrict__ bsums) {
    int i = blockIdx.x * 256 + threadIdx.x;
    if (i < N_NODES) offs[i] += bsums[blockIdx.x];
    if (i == 0) offs[N_NODES] = N_EDGES;
}

__global__ __launch_bounds__(256) void scatter_kernel(const int* __restrict__ src,
                                                      const int* __restrict__ dst,
                                                      const int* __restrict__ offs,
                                                      int* __restrict__ cur,
                                                      int* __restrict__ csr_src) {
    int e = blockIdx.x * 256 + threadIdx.x;
    if (e < N_EDGES) {
        int d = dst[e];
        int pos = offs[d] + atomicAdd(&cur[d], 1);
        csr_src[pos] = src[e];
    }
}

// ---------------- per-layer fused GEMM: q,k,v,(h@Ws+bs) ----------------
// block = 256 threads, 64 nodes/block.
// LDS: W all four matrices as [i][256] (64KB), reused as store staging.
__global__ __launch_bounds__(256) void gemm_qkvs(
    const float* __restrict__ h,
    const float* __restrict__ Wq, const float* __restrict__ Wk,
    const float* __restrict__ Wv, const float* __restrict__ Ws,
    const float* __restrict__ bq, const float* __restrict__ bk,
    const float* __restrict__ bv, const float* __restrict__ bs,
    float* __restrict__ q, float* __restrict__ kv, float* __restrict__ hnext) {
    __shared__ float smem[64 * 256];   // 64KB
    int t = threadIdx.x;
    int nb = blockIdx.x * 64;
    int lane = t & 63, chunk = t >> 6;

    const float* Wm  = (chunk == 0) ? Wq : (chunk == 1) ? Wk : (chunk == 2) ? Wv : Ws;
    const float* bm  = (chunk == 0) ? bq : (chunk == 1) ? bk : (chunk == 2) ? bv : bs;

    // cooperative W load: smem[i*256 + chunk*64 + j]
    for (int i = 0; i < 64; ++i)
        smem[i * 256 + t] = Wm[i * 64 + lane];

    // own h row -> registers
    int n = nb + lane;
    float4 hreg[16];
    const float4* hp = (const float4*)(h + (size_t)(n < N_NODES ? n : 0) * DIM);
    #pragma unroll
    for (int i4 = 0; i4 < 16; ++i4) hreg[i4] = hp[i4];
    if (n >= N_NODES) {
        #pragma unroll
        for (int i4 = 0; i4 < 16; ++i4) hreg[i4] = make_float4(0.f, 0.f, 0.f, 0.f);
    }

    float acc[64];
    #pragma unroll
    for (int j = 0; j < 64; ++j) acc[j] = bm[j];

    __syncthreads();

    const float* wbase = smem + chunk * 64;
    const float* hr = (const float*)hreg;
    #pragma unroll
    for (int i = 0; i < 64; ++i) {
        float hv = hr[i];
        const float4* wr = (const float4*)(wbase + i * 256);
        #pragma unroll
        for (int j4 = 0; j4 < 16; ++j4) {
            float4 w = wr[j4];
            acc[j4 * 4 + 0] += hv * w.x;
            acc[j4 * 4 + 1] += hv * w.y;
            acc[j4 * 4 + 2] += hv * w.z;
            acc[j4 * 4 + 3] += hv * w.w;
        }
    }
    __syncthreads();   // everyone done reading W; smem reusable

    // staged coalesced stores, one chunk at a time
    for (int c = 0; c < 4; ++c) {
        if (chunk == c) {
            #pragma unroll
            for (int j = 0; j < 64; ++j) smem[lane * 65 + j] = acc[j];
        }
        __syncthreads();
        #pragma unroll
        for (int it = 0; it < 16; ++it) {
            int idx = it * 256 + t;
            int nd = idx >> 6, j = idx & 63;
            int nn = nb + nd;
            if (nn < N_NODES) {
                float val = smem[nd * 65 + j];
                if (c == 0)      q[(size_t)nn * 64 + j] = val;
                else if (c == 1) kv[(size_t)nn * 128 + j] = val;
                else if (c == 2) kv[(size_t)nn * 128 + 64 + j] = val;
                else             hnext[(size_t)nn * 64 + j] = val;
            }
        }
        __syncthreads();
    }
}

// ---------------- edge attention: one wave per dst node, online softmax ----------------
__global__ __launch_bounds__(256) void edge_attn(
    const float* __restrict__ q, const float* __restrict__ kv,
    const int* __restrict__ offs, const int* __restrict__ csr_src,
    float* __restrict__ hnext) {
    int wave = threadIdx.x >> 6, lane = threadIdx.x & 63;
    int n = blockIdx.x * 4 + wave;
    if (n >= N_NODES) return;
    float qv = q[(size_t)n * 64 + lane];
    int e0 = offs[n], e1 = offs[n + 1];
    float m = -3.0e38f, z = 0.f, acc = 0.f;
    for (int e = e0; e < e1; ++e) {
        int src = csr_src[e];
        const float* kvp = kv + (size_t)src * 128;
        float kval = kvp[lane];
        float vval = kvp[64 + lane];
        float d = qv * kval;
        d += __shfl_xor(d, 1);
        d += __shfl_xor(d, 2);
        d += __shfl_xor(d, 4);
        d += __shfl_xor(d, 8);
        d += __shfl_xor(d, 16);
        d += __shfl_xor(d, 32);
        float alpha = d * 0.125f;             // 1/sqrt(64)
        float mn = fmaxf(m, alpha);
        float c = __expf(m - mn);
        float p = __expf(alpha - mn);
        z = z * c + p;
        acc = acc * c + p * vval;
        m = mn;
    }
    hnext[(size_t)n * 64 + lane] += acc / (z + 1e-16f);
}

// ---------------- pool + final linear ----------------
__device__ __forceinline__ int lbound(const int* a, int n, int key) {
    int lo = 0, hi = n;
    while (lo < hi) {
        int mid = (lo + hi) >> 1;
        if (a[mid] < key) lo = mid + 1; else hi = mid;
    }
    return lo;
}

__global__ __launch_bounds__(256) void pool_out(const float* __restrict__ h,
                                                const int* __restrict__ batch,
                                                const float* __restrict__ Wf,
                                                const float* __restrict__ bf,
                                                float* __restrict__ out) {
    __shared__ float ps[4][64];
    __shared__ float pl[64];
    int g = blockIdx.x, t = threadIdx.x;
    int lo = lbound(batch, N_NODES, g);
    int hi = lbound(batch, N_NODES, g + 1);
    int cnt = hi - lo;
    int sub = t >> 6, d = t & 63;
    float a = 0.f;
    for (int n2 = lo + sub; n2 < hi; n2 += 4) a += h[(size_t)n2 * 64 + d];
    ps[sub][d] = a;
    __syncthreads();
    if (t < 64) {
        float s = ps[0][t] + ps[1][t] + ps[2][t] + ps[3][t];
        pl[t] = s / (float)(cnt > 1 ? cnt : 1);
    }
    __syncthreads();
    if (t < OUT_DIM) {
        float o = bf[t];
        for (int d2 = 0; d2 < 64; ++d2) o += pl[d2] * Wf[d2 * OUT_DIM + t];
        out[g * OUT_DIM + t] = o;
    }
}

// ---------------- launch ----------------
extern "C" void kernel_launch(void* const* d_in, const int* in_sizes, int n_in,
                              void* d_out, int out_size, void* d_ws, size_t ws_size,
                              hipStream_t stream) {
    const float* x    = (const float*)d_in[0];
    const int*   ei   = (const int*)d_in[1];
    const int*   batch= (const int*)d_in[2];
    const float* Wq   = (const float*)d_in[3];
    const float* bq   = (const float*)d_in[4];
    const float* Wk   = (const float*)d_in[5];
    const float* bk   = (const float*)d_in[6];
    const float* Wv   = (const float*)d_in[7];
    const float* bv   = (const float*)d_in[8];
    const float* Ws   = (const float*)d_in[9];
    const float* bs   = (const float*)d_in[10];
    const float* Wf   = (const float*)d_in[11];
    const float* bf   = (const float*)d_in[12];
    float* out = (float*)d_out;

    char* ws = (char*)d_ws;
    float* qb   = (float*)(ws + 0);            // 12.8MB
    float* kvb  = (float*)(ws + 12800000);     // 25.6MB
    float* hA   = (float*)(ws + 38400000);     // 12.8MB
    float* hB   = (float*)(ws + 51200000);     // 12.8MB
    int*   csr  = (int*)  (ws + 64000000);     // 3.2MB
    int*   offs = (int*)  (ws + 67200000);     // 200004 B
    int*   cur  = (int*)  (ws + 67400704);     // 200000 B
    int*   bsums= (int*)  (ws + 67600704);     // ~1KB

    const int* srcI = ei;
    const int* dstI = ei + N_EDGES;

    // CSR build (recomputed every call; deterministic work)
    hipMemsetAsync(cur, 0, N_NODES * sizeof(int), stream);
    count_kernel<<<N_EDGES / 256, 256, 0, stream>>>(dstI, cur);
    scan1<<<NBLK_N, 256, 0, stream>>>(cur, offs, bsums);
    scan2<<<1, 256, 0, stream>>>(bsums, NBLK_N);
    scan3<<<NBLK_N, 256, 0, stream>>>(offs, bsums);
    hipMemsetAsync(cur, 0, N_NODES * sizeof(int), stream);
    scatter_kernel<<<N_EDGES / 256, 256, 0, stream>>>(srcI, dstI, offs, cur, csr);

    const float* hin = x;
    float* hout = hA;
    for (int l = 0; l < 4; ++l) {
        gemm_qkvs<<<(N_NODES + 63) / 64, 256, 0, stream>>>(
            hin, Wq + l * 4096, Wk + l * 4096, Wv + l * 4096, Ws + l * 4096,
            bq + l * 64, bk + l * 64, bv + l * 64, bs + l * 64,
            qb, kvb, hout);
        edge_attn<<<N_NODES / 4, 256, 0, stream>>>(qb, kvb, offs, csr, hout);
        hin = hout;
        hout = (hout == hA) ? hB : hA;
    }
    pool_out<<<N_GRAPHS, 256, 0, stream>>>(hin, batch, Wf, bf, out);
}